// Round 2
// baseline (237.470 us; speedup 1.0000x reference)
//
#include <hip/hip_runtime.h>

// CSPN propagation step:
// out[b,0,y,x] = sum_{k=0..8, k!=4} aff[b,k,y,x] * cur[b,0,y+dy-1,x+dx-1]  (zero pad)
//              + aff[b,4,y,x] * coarse[b,0,y,x]
// where k = dy*3 + dx.
// Memory-bound: ~201 MB traffic -> target ~32 us at 6.3 TB/s.

__global__ __launch_bounds__(256) void cspn_kernel(
    const float* __restrict__ aff,
    const float* __restrict__ cur,
    const float* __restrict__ coarse,
    float* __restrict__ out,
    int B, int H, int W)
{
    const int W4 = W >> 2;                 // float4s per row
    const int total = B * H * W4;
    int t = blockIdx.x * blockDim.x + threadIdx.x;
    if (t >= total) return;

    const int xq   = t % W4;
    const int rest = t / W4;
    const int y    = rest % H;
    const int b    = rest / H;
    const int x0   = xq << 2;

    const size_t plane = (size_t)H * W;
    const float* curb  = cur + (size_t)b * plane;
    const size_t rowoff = (size_t)y * W + x0;

    // Middle row of cur_seg (always in range)
    float4 md = *(const float4*)(curb + rowoff);
    float mdl = 0.f, mdr = 0.f;
    if (x0 > 0)     mdl = curb[rowoff - 1];
    if (x0 + 4 < W) mdr = curb[rowoff + 4];

    // Upper row (y-1), zero if out of range
    float4 up = make_float4(0.f, 0.f, 0.f, 0.f);
    float upl = 0.f, upr = 0.f;
    if (y > 0) {
        const size_t o = rowoff - (size_t)W;
        up = *(const float4*)(curb + o);
        if (x0 > 0)     upl = curb[o - 1];
        if (x0 + 4 < W) upr = curb[o + 4];
    }

    // Lower row (y+1)
    float4 dn = make_float4(0.f, 0.f, 0.f, 0.f);
    float dnl = 0.f, dnr = 0.f;
    if (y + 1 < H) {
        const size_t o = rowoff + (size_t)W;
        dn = *(const float4*)(curb + o);
        if (x0 > 0)     dnl = curb[o - 1];
        if (x0 + 4 < W) dnr = curb[o + 4];
    }

    // Center tap replacement
    float4 co = *(const float4*)(coarse + (size_t)b * plane + rowoff);

    // 9 affinity channels, coalesced float4 loads (stride = plane between k)
    const float* affb = aff + (size_t)b * 9 * plane + rowoff;
    float4 a[9];
    #pragma unroll
    for (int k = 0; k < 9; ++k)
        a[k] = *(const float4*)(affb + (size_t)k * plane);

    // Shifted neighbor values per output lane j = x0..x0+3:
    //   left  (dx=0): {l, v.x, v.y, v.z}
    //   center(dx=1): v
    //   right (dx=2): {v.y, v.z, v.w, r}
    float4 r;
    r.x = a[0].x*upl  + a[1].x*up.x + a[2].x*up.y
        + a[3].x*mdl  + a[4].x*co.x + a[5].x*md.y
        + a[6].x*dnl  + a[7].x*dn.x + a[8].x*dn.y;
    r.y = a[0].y*up.x + a[1].y*up.y + a[2].y*up.z
        + a[3].y*md.x + a[4].y*co.y + a[5].y*md.z
        + a[6].y*dn.x + a[7].y*dn.y + a[8].y*dn.z;
    r.z = a[0].z*up.y + a[1].z*up.z + a[2].z*up.w
        + a[3].z*md.y + a[4].z*co.z + a[5].z*md.w
        + a[6].z*dn.y + a[7].z*dn.z + a[8].z*dn.w;
    r.w = a[0].w*up.z + a[1].w*up.w + a[2].w*upr
        + a[3].w*md.z + a[4].w*co.w + a[5].w*mdr
        + a[6].w*dn.z + a[7].w*dn.w + a[8].w*dnr;

    *(float4*)(out + (size_t)b * plane + rowoff) = r;
}

extern "C" void kernel_launch(void* const* d_in, const int* in_sizes, int n_in,
                              void* d_out, int out_size, void* d_ws, size_t ws_size,
                              hipStream_t stream) {
    const float* aff    = (const float*)d_in[0];  // [16, 9, 512, 512]
    const float* cur    = (const float*)d_in[1];  // [16, 1, 512, 512]
    const float* coarse = (const float*)d_in[2];  // [16, 1, 512, 512]
    // d_in[3] is the scalar `i` (unused by the computation)
    float* out = (float*)d_out;                   // [16, 1, 512, 512]

    const int B = 16, H = 512, W = 512;
    const int total = B * H * (W >> 2);           // one float4 per thread
    const int block = 256;
    const int grid  = (total + block - 1) / block;

    cspn_kernel<<<grid, block, 0, stream>>>(aff, cur, coarse, out, B, H, W);
}

// Round 3
// 236.877 us; speedup vs baseline: 1.0025x; 1.0025x over previous
//
#include <hip/hip_runtime.h>

// CSPN propagation step, row-per-wave formulation.
// out[b,0,y,x] = sum_{k=0..8, k!=4} aff[b,k,y,x] * cur[b,0,y+dy-1,x+dx-1] (zero pad)
//              + aff[b,4,y,x] * coarse[b,0,y,x],  k = dy*3+dx.
//
// W=512 = 64 lanes * 8 floats: one wave owns one row; x-halos via __shfl,
// y-border branches are wave-uniform. Affinity is read-once -> nontemporal.

typedef float f4 __attribute__((ext_vector_type(4)));

constexpr int Bc = 16, Hc = 512, Wc = 512;

__global__ __launch_bounds__(256) void cspn_kernel(
    const float* __restrict__ aff,
    const float* __restrict__ cur,
    const float* __restrict__ coarse,
    float* __restrict__ out)
{
    const int lane = threadIdx.x & 63;
    const int row  = (blockIdx.x << 2) + (threadIdx.x >> 6);  // 0..B*H-1
    const int y    = row & (Hc - 1);
    const int b    = row >> 9;                                // row / H
    const int plane = Hc * Wc;
    const int rb   = row * Wc;                                // b*plane + y*W
    const int xo   = lane << 3;                               // 8 px per lane

    const float* curp = cur + rb + xo;

    // cur rows: middle always valid; up/dn zero at y borders (wave-uniform)
    f4 mp = *(const f4*)(curp);
    f4 mq = *(const f4*)(curp + 4);
    f4 up = (f4)(0.f), uq = (f4)(0.f), dp = (f4)(0.f), dq = (f4)(0.f);
    if (y > 0)      { up = *(const f4*)(curp - Wc); uq = *(const f4*)(curp - Wc + 4); }
    if (y < Hc - 1) { dp = *(const f4*)(curp + Wc); dq = *(const f4*)(curp + Wc + 4); }
    f4 cp = *(const f4*)(coarse + rb + xo);
    f4 cq = *(const f4*)(coarse + rb + xo + 4);

    // x-halos from neighbor lanes (zero at global x borders)
    float uL = __shfl_up(uq.w, 1);   if (lane == 0)  uL = 0.f;
    float mL = __shfl_up(mq.w, 1);   if (lane == 0)  mL = 0.f;
    float dL = __shfl_up(dq.w, 1);   if (lane == 0)  dL = 0.f;
    float uR = __shfl_down(up.x, 1); if (lane == 63) uR = 0.f;
    float mR = __shfl_down(mp.x, 1); if (lane == 63) mR = 0.f;
    float dR = __shfl_down(dp.x, 1); if (lane == 63) dR = 0.f;

    // 10-wide shifted windows: arr[e+dx] = row value at x = xo+e+dx-1
    const float u[10] = {uL, up.x,up.y,up.z,up.w, uq.x,uq.y,uq.z,uq.w, uR};
    const float m[10] = {mL, mp.x,mp.y,mp.z,mp.w, mq.x,mq.y,mq.z,mq.w, mR};
    const float d[10] = {dL, dp.x,dp.y,dp.z,dp.w, dq.x,dq.y,dq.z,dq.w, dR};
    const float c[8]  = {cp.x,cp.y,cp.z,cp.w, cq.x,cq.y,cq.z,cq.w};

    const float* ab = aff + b * 9 * plane + y * Wc + xo;

    float acc[8];

#define TAP0(K, S) {                                                          \
    f4 A0 = __builtin_nontemporal_load((const f4*)(ab + (K) * plane));        \
    f4 A1 = __builtin_nontemporal_load((const f4*)(ab + (K) * plane + 4));    \
    acc[0] = A0.x*(S)[0]; acc[1] = A0.y*(S)[1];                               \
    acc[2] = A0.z*(S)[2]; acc[3] = A0.w*(S)[3];                               \
    acc[4] = A1.x*(S)[4]; acc[5] = A1.y*(S)[5];                               \
    acc[6] = A1.z*(S)[6]; acc[7] = A1.w*(S)[7]; }
#define TAP(K, S) {                                                           \
    f4 A0 = __builtin_nontemporal_load((const f4*)(ab + (K) * plane));        \
    f4 A1 = __builtin_nontemporal_load((const f4*)(ab + (K) * plane + 4));    \
    acc[0] += A0.x*(S)[0]; acc[1] += A0.y*(S)[1];                             \
    acc[2] += A0.z*(S)[2]; acc[3] += A0.w*(S)[3];                             \
    acc[4] += A1.x*(S)[4]; acc[5] += A1.y*(S)[5];                             \
    acc[6] += A1.z*(S)[6]; acc[7] += A1.w*(S)[7]; }

    TAP0(0, u);      // up, dx=0  (x-1)
    TAP (1, u + 1);  // up, dx=1
    TAP (2, u + 2);  // up, dx=2  (x+1)
    TAP (3, m);      // mid, dx=0
    TAP (4, c);      // center tap -> coarse
    TAP (5, m + 2);  // mid, dx=2
    TAP (6, d);      // dn, dx=0
    TAP (7, d + 1);  // dn, dx=1
    TAP (8, d + 2);  // dn, dx=2
#undef TAP0
#undef TAP

    f4 r0 = {acc[0], acc[1], acc[2], acc[3]};
    f4 r1 = {acc[4], acc[5], acc[6], acc[7]};
    __builtin_nontemporal_store(r0, (f4*)(out + rb + xo));
    __builtin_nontemporal_store(r1, (f4*)(out + rb + xo + 4));
}

extern "C" void kernel_launch(void* const* d_in, const int* in_sizes, int n_in,
                              void* d_out, int out_size, void* d_ws, size_t ws_size,
                              hipStream_t stream) {
    const float* aff    = (const float*)d_in[0];  // [16, 9, 512, 512]
    const float* cur    = (const float*)d_in[1];  // [16, 1, 512, 512]
    const float* coarse = (const float*)d_in[2];  // [16, 1, 512, 512]
    float* out = (float*)d_out;                   // [16, 1, 512, 512]

    const int rows  = Bc * Hc;        // 8192 rows, 1 wave each
    const int block = 256;            // 4 waves per block
    const int grid  = rows / 4;       // 2048 blocks

    cspn_kernel<<<grid, block, 0, stream>>>(aff, cur, coarse, out);
}